// Round 7
// baseline (95.524 us; speedup 1.0000x reference)
//
#include <hip/hip_runtime.h>

#define BB 8
#define CC 256
#define HH 96
#define WW 96
#define HWW (HH*WW)
#define NLOC 256        // local prototypes (MFMA path)
#define PPAD 257        // + global prototype
#define THRESH 0.95f
#define NORM_EPS 1e-4f

typedef __attribute__((ext_vector_type(8))) short bf16x8;
typedef __attribute__((ext_vector_type(4))) float f32x4;

// ---- fused kernel 0+1: mask pooling (8 blocks) + feature pooling (2048) ----
__global__ void k01(const float* __restrict__ sup_fts,
                    const float* __restrict__ sup_mask,
                    const float* __restrict__ true_bg,
                    float* __restrict__ protos,
                    float* __restrict__ validf,
                    float* __restrict__ masksum) {
    __shared__ float red[256];
    int blk = blockIdx.x;
    int t = threadIdx.x;
    if (blk < BB * CC) {
        int b = blk >> 8, c = blk & 255;
        int gy = t >> 4, gx = t & 15;
        const float* fb = sup_fts + ((size_t)b * CC + c) * HWW;
        const float* mb = sup_mask + (size_t)b * HWW;
        int base = gy * 6 * WW + gx * 6;
        float fs = 0.f, fm = 0.f;
        for (int r = 0; r < 6; ++r) {
            const float* rowf = fb + base + r * WW;
            const float* rowm = mb + base + r * WW;
#pragma unroll
            for (int h = 0; h < 3; ++h) {
                float2 v  = *(const float2*)(rowf + 2 * h);
                float2 mk = *(const float2*)(rowm + 2 * h);
                fs += v.x + v.y;
                fm = fmaf(v.x, mk.x, fm);
                fm = fmaf(v.y, mk.y, fm);
            }
        }
        protos[((size_t)b * PPAD + t) * CC + c] = fs * (1.f / 36.f);
        red[t] = fm;
        __syncthreads();
        for (int off = 128; off > 0; off >>= 1) {
            if (t < off) red[t] += red[t + off];
            __syncthreads();
        }
        if (t == 0) protos[((size_t)b * PPAD + 256) * CC + c] = red[0];
    } else {
        int b = blk - BB * CC;
        int gy = t >> 4, gx = t & 15;
        const float* mb = sup_mask + (size_t)b * HWW;
        const float* gb = true_bg  + (size_t)b * HWW;
        int base = gy * 6 * WW + gx * 6;
        float ms = 0.f, bs = 0.f;
        for (int r = 0; r < 6; ++r) {
            const float* rowm = mb + base + r * WW;
            const float* rowg = gb + base + r * WW;
#pragma unroll
            for (int h = 0; h < 3; ++h) {
                float2 mk = *(const float2*)(rowm + 2 * h);
                float2 bg2 = *(const float2*)(rowg + 2 * h);
                ms += mk.x + mk.y;
                bs += bg2.x + bg2.y;
            }
        }
        float mmean = ms * (1.f / 36.f);
        float bmean = bs * (1.f / 36.f);
        validf[b * PPAD + t] = (mmean > THRESH && bmean < 0.5f) ? 1.f : 0.f;
        if (t == 0) validf[b * PPAD + 256] = 1.f;
        red[t] = ms;
        __syncthreads();
        for (int off = 128; off > 0; off >>= 1) {
            if (t < off) red[t] += red[t + off];
            __syncthreads();
        }
        if (t == 0) masksum[b] = red[0];
    }
}

// ------- kernel 2: finish gproto + normalize + emit bf16 hi/lo B-image ------
// Bimg layout (ushorts): [B][8 kc][2 hilo][256 p][32 j]
__global__ void k2_norm(float* __restrict__ protos,
                        const float* __restrict__ masksum,
                        unsigned short* __restrict__ Bimg) {
    int bp = blockIdx.x;
    int b = bp / PPAD;
    int p = bp - b * PPAD;
    int t = threadIdx.x;            // channel
    float v = protos[((size_t)b * PPAD + p) * CC + t];
    if (p == 256) v = v / (masksum[b] + 1e-5f);
    __shared__ float red[256];
    red[t] = v * v;
    __syncthreads();
    for (int off = 128; off > 0; off >>= 1) {
        if (t < off) red[t] += red[t + off];
        __syncthreads();
    }
    float norm = sqrtf(red[0]);
    float vn = v / fmaxf(norm, NORM_EPS);
    protos[((size_t)b * PPAD + p) * CC + t] = vn;
    if (p < NLOC) {
        unsigned int u = __float_as_uint(vn);
        unsigned short hi = (unsigned short)(u >> 16);          // truncation
        float lo = vn - __uint_as_float(u & 0xffff0000u);       // exact
        unsigned int ul = __float_as_uint(lo);
        unsigned short lob = (unsigned short)((ul + 0x7fffu + ((ul >> 16) & 1u)) >> 16); // RNE
        int kc = t >> 5, j = t & 31;
        size_t base = ((size_t)(b * 8 + kc) * 2) * 8192;
        Bimg[base + (size_t)p * 32 + j] = hi;                   // hilo=0
        Bimg[base + 8192 + (size_t)p * 32 + j] = lob;           // hilo=1
    }
}

// ---------------- kernel 3: MFMA dists + masked softmax + weighted sum ------
// Block = 1024 thr = 16 waves; block owns 64 px x all 257 protos.
// Wave w holds protos [16w,16w+16) as STATIONARY A-register fragments
// (hi+lo, 64 VGPR, loaded once). q is the moving B operand: per kc all
// threads load q (float2, coalesced), split fp32->bf16 hi/lo, stage to
// LDS; waves read B-frags back. The loop's ONLY VMEM stream is q ->
// compiler vmcnt waits count q exactly (no entanglement); barriers are
// raw s_barrier with lgkmcnt(0)-only drain -> 3-deep q prefetch is
// never drained (the round-4/6 killer was vmcnt(0) at __syncthreads).
#define LBAR()  do {                                             \
        asm volatile("s_waitcnt lgkmcnt(0)" ::: "memory");       \
        __builtin_amdgcn_sched_barrier(0);                       \
        __builtin_amdgcn_s_barrier();                            \
        __builtin_amdgcn_sched_barrier(0);                       \
    } while (0)

__global__ __launch_bounds__(1024, 4)
void k3_mfma(const float* __restrict__ qry,
             const unsigned short* __restrict__ Bimg,
             const float* __restrict__ protos_n,
             const float* __restrict__ validf,
             float* __restrict__ out) {
    __shared__ alignas(16) unsigned short Qlds[2][2][2560]; // [buf][hi/lo][64px*40pad]
    __shared__ float nrm_l[32][64];
    __shared__ float gac_l[32][64];
    __shared__ float S_l[16][64];
    __shared__ float N_l[16][64];
    __shared__ float rn_s[64], gd_s[64];

    int bid = blockIdx.x;
    int b = bid / 144;
    int tile = bid - b * 144;
    int t = threadIdx.x;              // 0..1023
    int lane = t & 63;
    int w = t >> 6;                   // wave 0..15
    int g = lane >> 4;                // k-group
    int n = lane & 15;                // frag 16-lane index
    int px0 = tile * 64;

    int cl = t >> 5;                  // staging: ch slot 0..31
    int pp = (t & 31) * 2;            // staging: px pair base

    const float* qb = qry + (size_t)b * CC * HWW + px0 + pp;
    const float* gp = protos_n + ((size_t)b * PPAD + 256) * CC;
    const unsigned short* Bb = Bimg + (size_t)b * 8 * 2 * 8192;

    // ---- stationary proto A-frags: wave w protos [16w..16w+16), all 8 kc --
    bf16x8 PH[8], PL[8];
#pragma unroll
    for (int kc = 0; kc < 8; ++kc) {
        const unsigned short* p0 = Bb + (size_t)kc * 16384 + (w * 16 + n) * 32 + g * 8;
        PH[kc] = *(const bf16x8*)(p0);
        PL[kc] = *(const bf16x8*)(p0 + 8192);
    }
    float gpv8[8];
#pragma unroll
    for (int kc = 0; kc < 8; ++kc) gpv8[kc] = gp[kc * 32 + cl];

    f32x4 acc[4];
#pragma unroll
    for (int s = 0; s < 4; ++s) acc[s] = (f32x4){0.f, 0.f, 0.f, 0.f};
    float nrm2[2] = {0.f, 0.f};
    float gac2[2] = {0.f, 0.f};
    float2 qs[3];

#define QLOAD(KC, SLOT)                                                       \
    qs[SLOT] = *(const float2*)(qb + (size_t)((KC) * 32 + cl) * HWW);

#define SPLIT(KC, SLOT, BUF)                                                  \
    {                                                                         \
        float2 qv = qs[SLOT];                                                 \
        unsigned int ux = __float_as_uint(qv.x);                              \
        unsigned int uy = __float_as_uint(qv.y);                              \
        unsigned short hx = (unsigned short)(ux >> 16);                       \
        unsigned short hy = (unsigned short)(uy >> 16);                       \
        float lxf = qv.x - __uint_as_float(ux & 0xffff0000u);                 \
        float lyf = qv.y - __uint_as_float(uy & 0xffff0000u);                 \
        unsigned int ulx = __float_as_uint(lxf);                              \
        unsigned int uly = __float_as_uint(lyf);                              \
        unsigned short lx = (unsigned short)((ulx + 0x7fffu + ((ulx >> 16) & 1u)) >> 16); \
        unsigned short ly = (unsigned short)((uly + 0x7fffu + ((uly >> 16) & 1u)) >> 16); \
        Qlds[BUF][0][pp * 40 + cl] = hx;                                      \
        Qlds[BUF][0][(pp + 1) * 40 + cl] = hy;                                \
        Qlds[BUF][1][pp * 40 + cl] = lx;                                      \
        Qlds[BUF][1][(pp + 1) * 40 + cl] = ly;                                \
        nrm2[0] = fmaf(qv.x, qv.x, nrm2[0]);                                  \
        nrm2[1] = fmaf(qv.y, qv.y, nrm2[1]);                                  \
        float gpc = gpv8[KC];                                                 \
        gac2[0] = fmaf(qv.x, gpc, gac2[0]);                                   \
        gac2[1] = fmaf(qv.y, gpc, gac2[1]);                                   \
    }

    // ---- prologue: 3-deep q prefetch, split kc=0, publish ----
    QLOAD(0, 0);
    QLOAD(1, 1);
    QLOAD(2, 2);
    SPLIT(0, 0, 0);                  // compiler waits q0 only (q1,q2 younger)
    LBAR();

    // ---- main loop: pure-q VMEM stream, lgkm-only barriers ----
#pragma unroll
    for (int kc = 0; kc < 8; ++kc) {
        if (kc + 3 < 8) { QLOAD(kc + 3, (kc + 3) % 3); }
#pragma unroll
        for (int sub = 0; sub < 4; ++sub) {
            bf16x8 QH = *(const bf16x8*)&Qlds[kc & 1][0][(sub * 16 + n) * 40 + g * 8];
            bf16x8 QL = *(const bf16x8*)&Qlds[kc & 1][1][(sub * 16 + n) * 40 + g * 8];
            acc[sub] = __builtin_amdgcn_mfma_f32_16x16x32_bf16(PH[kc], QH, acc[sub], 0, 0, 0);
            acc[sub] = __builtin_amdgcn_mfma_f32_16x16x32_bf16(PL[kc], QH, acc[sub], 0, 0, 0);
            acc[sub] = __builtin_amdgcn_mfma_f32_16x16x32_bf16(PH[kc], QL, acc[sub], 0, 0, 0);
        }
        if (kc + 1 < 8) {
            SPLIT(kc + 1, (kc + 1) % 3, (kc + 1) & 1);
            LBAR();
        }
    }

    // ---- |q|^2 and gproto-dot reduction (32 ch-slots per px) ----
    nrm_l[cl][pp] = nrm2[0]; nrm_l[cl][pp + 1] = nrm2[1];
    gac_l[cl][pp] = gac2[0]; gac_l[cl][pp + 1] = gac2[1];
    __syncthreads();
    if (t < 64) {
        float n2 = 0.f, gs = 0.f;
#pragma unroll
        for (int i = 0; i < 32; ++i) { n2 += nrm_l[i][t]; gs += gac_l[i][t]; }
        float rn = 1.f / fmaxf(sqrtf(n2), NORM_EPS);
        rn_s[t] = rn;
        gd_s[t] = gs * rn;
    }
    __syncthreads();

    // ---- per-wave softmax partials (fixed shift 1.1; 16 protos/wave) ----
    // D-map: proto = 16w + 4g + r, px = sub*16 + n.
    float vfr[4];
#pragma unroll
    for (int r = 0; r < 4; ++r) vfr[r] = validf[b * PPAD + w * 16 + 4 * g + r];
#pragma unroll
    for (int sub = 0; sub < 4; ++sub) {
        float rnv = rn_s[sub * 16 + n];
        float s = 0.f, nn = 0.f;
#pragma unroll
        for (int r = 0; r < 4; ++r) {
            float d = acc[sub][r] * rnv;
            float l = (vfr[r] != 0.f) ? d : -1e30f;
            float e = __expf(l - 1.1f);       // masked -> exactly 0
            s += e;
            nn = fmaf(e, l, nn);
        }
        s  += __shfl_xor(s, 16);  s  += __shfl_xor(s, 32);
        nn += __shfl_xor(nn, 16); nn += __shfl_xor(nn, 32);
        if (g == sub) { S_l[w][sub * 16 + n] = s; N_l[w][sub * 16 + n] = nn; }
    }
    __syncthreads();

    // ---- final merge: 16 wave-partials + global proto (once), store ----
    if (t < 64) {
        float gdv = gd_s[t];
        float eg = __expf(gdv - 1.1f);
        float S = eg, N = eg * gdv;
#pragma unroll
        for (int i = 0; i < 16; ++i) { S += S_l[i][t]; N += N_l[i][t]; }
        out[(size_t)b * HWW + px0 + t] = N / S;
    }

#undef QLOAD
#undef SPLIT
}

extern "C" void kernel_launch(void* const* d_in, const int* in_sizes, int n_in,
                              void* d_out, int out_size, void* d_ws, size_t ws_size,
                              hipStream_t stream) {
    const float* qry = (const float*)d_in[0];
    const float* sup = (const float*)d_in[1];
    const float* msk = (const float*)d_in[2];
    const float* bg  = (const float*)d_in[3];
    float* out = (float*)d_out;

    float* ws = (float*)d_ws;
    float* protos  = ws;                                   // [B][257][256] f32
    float* validf  = protos + (size_t)BB * PPAD * CC;      // [B][257]
    float* masksum = validf + (size_t)BB * PPAD;           // [B]
    unsigned short* Bimg = (unsigned short*)(masksum + BB); // [B][8][2][256][32] ushorts

    hipLaunchKernelGGL(k01, dim3(BB * CC + BB), dim3(256), 0, stream,
                       sup, msk, bg, protos, validf, masksum);
    hipLaunchKernelGGL(k2_norm, dim3(BB * PPAD), dim3(256), 0, stream, protos, masksum, Bimg);
    hipLaunchKernelGGL(k3_mfma, dim3(BB * (HWW / 64)), dim3(1024), 0, stream,
                       qry, Bimg, protos, validf, out);
}

// Round 8
// 70.883 us; speedup vs baseline: 1.3476x; 1.3476x over previous
//
#include <hip/hip_runtime.h>

#define BB 8
#define CC 256
#define HH 96
#define WW 96
#define HWW (HH*WW)
#define NLOC 256        // local prototypes (MFMA path)
#define PPAD 257        // + global prototype
#define THRESH 0.95f
#define NORM_EPS 1e-4f

typedef __attribute__((ext_vector_type(8))) short bf16x8;
typedef __attribute__((ext_vector_type(4))) float f32x4;

// ---- fused kernel 0+1: mask pooling (8 blocks) + feature pooling (2048) ----
__global__ void k01(const float* __restrict__ sup_fts,
                    const float* __restrict__ sup_mask,
                    const float* __restrict__ true_bg,
                    float* __restrict__ protos,
                    float* __restrict__ validf,
                    float* __restrict__ masksum) {
    __shared__ float red[256];
    int blk = blockIdx.x;
    int t = threadIdx.x;
    if (blk < BB * CC) {
        int b = blk >> 8, c = blk & 255;
        int gy = t >> 4, gx = t & 15;
        const float* fb = sup_fts + ((size_t)b * CC + c) * HWW;
        const float* mb = sup_mask + (size_t)b * HWW;
        int base = gy * 6 * WW + gx * 6;
        float fs = 0.f, fm = 0.f;
        for (int r = 0; r < 6; ++r) {
            const float* rowf = fb + base + r * WW;
            const float* rowm = mb + base + r * WW;
#pragma unroll
            for (int h = 0; h < 3; ++h) {
                float2 v  = *(const float2*)(rowf + 2 * h);
                float2 mk = *(const float2*)(rowm + 2 * h);
                fs += v.x + v.y;
                fm = fmaf(v.x, mk.x, fm);
                fm = fmaf(v.y, mk.y, fm);
            }
        }
        protos[((size_t)b * PPAD + t) * CC + c] = fs * (1.f / 36.f);
        red[t] = fm;
        __syncthreads();
        for (int off = 128; off > 0; off >>= 1) {
            if (t < off) red[t] += red[t + off];
            __syncthreads();
        }
        if (t == 0) protos[((size_t)b * PPAD + 256) * CC + c] = red[0];
    } else {
        int b = blk - BB * CC;
        int gy = t >> 4, gx = t & 15;
        const float* mb = sup_mask + (size_t)b * HWW;
        const float* gb = true_bg  + (size_t)b * HWW;
        int base = gy * 6 * WW + gx * 6;
        float ms = 0.f, bs = 0.f;
        for (int r = 0; r < 6; ++r) {
            const float* rowm = mb + base + r * WW;
            const float* rowg = gb + base + r * WW;
#pragma unroll
            for (int h = 0; h < 3; ++h) {
                float2 mk = *(const float2*)(rowm + 2 * h);
                float2 bg2 = *(const float2*)(rowg + 2 * h);
                ms += mk.x + mk.y;
                bs += bg2.x + bg2.y;
            }
        }
        float mmean = ms * (1.f / 36.f);
        float bmean = bs * (1.f / 36.f);
        validf[b * PPAD + t] = (mmean > THRESH && bmean < 0.5f) ? 1.f : 0.f;
        if (t == 0) validf[b * PPAD + 256] = 1.f;
        red[t] = ms;
        __syncthreads();
        for (int off = 128; off > 0; off >>= 1) {
            if (t < off) red[t] += red[t + off];
            __syncthreads();
        }
        if (t == 0) masksum[b] = red[0];
    }
}

// ------- kernel 2: finish gproto + normalize + emit bf16 hi/lo B-image ------
// Bimg layout (ushorts): [B][8 kc][2 hilo][256 p][32 j]
__global__ void k2_norm(float* __restrict__ protos,
                        const float* __restrict__ masksum,
                        unsigned short* __restrict__ Bimg) {
    int bp = blockIdx.x;
    int b = bp / PPAD;
    int p = bp - b * PPAD;
    int t = threadIdx.x;            // channel
    float v = protos[((size_t)b * PPAD + p) * CC + t];
    if (p == 256) v = v / (masksum[b] + 1e-5f);
    __shared__ float red[256];
    red[t] = v * v;
    __syncthreads();
    for (int off = 128; off > 0; off >>= 1) {
        if (t < off) red[t] += red[t + off];
        __syncthreads();
    }
    float norm = sqrtf(red[0]);
    float vn = v / fmaxf(norm, NORM_EPS);
    protos[((size_t)b * PPAD + p) * CC + t] = vn;
    if (p < NLOC) {
        unsigned int u = __float_as_uint(vn);
        unsigned short hi = (unsigned short)(u >> 16);          // truncation
        float lo = vn - __uint_as_float(u & 0xffff0000u);       // exact
        unsigned int ul = __float_as_uint(lo);
        unsigned short lob = (unsigned short)((ul + 0x7fffu + ((ul >> 16) & 1u)) >> 16); // RNE
        int kc = t >> 5, j = t & 31;
        size_t base = ((size_t)(b * 8 + kc) * 2) * 8192;
        Bimg[base + (size_t)p * 32 + j] = hi;                   // hilo=0
        Bimg[base + 8192 + (size_t)p * 32 + j] = lob;           // hilo=1
    }
}

// ---------------- kernel 3: MFMA dists + masked softmax + weighted sum ------
// Round-6 structure (block = 512 thr = 8 waves, 64 px, wave owns 32 protos,
// q split-staged in LDS dbuf, B streamed L2->regs) with two fixes:
//  (a) main-loop barriers are raw s_barrier + lgkmcnt(0)-only drain (LBAR)
//      -> the compiler's vmcnt(0)-before-__syncthreads no longer drains the
//      2-deep q/B prefetch every kc (round-4/6 killer);
//  (b) Q-LDS rows interleave hi/lo per k-quad: each staging thread writes ONE
//      uint4 (16B) into 144B-padded rows (2 lanes/bank/clock = minimal);
//      readers reassemble hi/lo frags from dword halves (zero extra ops).
#define LBAR()  do {                                             \
        asm volatile("s_waitcnt lgkmcnt(0)" ::: "memory");       \
        __builtin_amdgcn_sched_barrier(0);                       \
        __builtin_amdgcn_s_barrier();                            \
        __builtin_amdgcn_sched_barrier(0);                       \
    } while (0)

__global__ __launch_bounds__(512, 4)
void k3_mfma(const float* __restrict__ qry,
             const unsigned short* __restrict__ Bimg,
             const float* __restrict__ protos_n,
             const float* __restrict__ validf,
             float* __restrict__ out) {
    // [buf][64 px rows of 72 ushorts: 8 kquads x (4 hi | 4 lo), 8-ushort pad]
    __shared__ alignas(16) unsigned short Qlds[2][4608];   // 18432 B
    __shared__ float nrm_l[8][64], gac_l[8][64];
    __shared__ float S_l[8][64], N_l[8][64];
    __shared__ float rn_s[64], gd_s[64];

    int bid = blockIdx.x;
    int b = bid / 144;
    int tile = bid - b * 144;
    int t = threadIdx.x;              // 0..511
    int lane = t & 63;
    int w = t >> 6;                   // wave 0..7
    int g = lane >> 4;                // k-group
    int n = lane & 15;                // frag 16-lane index
    int px0 = tile * 64;

    int spx = t & 63;                 // staging: pixel owned by this thread
    int kq  = t >> 6;                 // staging: k-quad (4 channels) 0..7

    const float* qb = qry + (size_t)b * CC * HWW + px0 + spx;
    const float* gp = protos_n + ((size_t)b * PPAD + 256) * CC;
    const unsigned short* Bb = Bimg + (size_t)b * 8 * 2 * 8192;

    f32x4 acc[4][2];                  // [px-sub][ct]: 64px x 32 protos
#pragma unroll
    for (int s = 0; s < 4; ++s)
#pragma unroll
        for (int c = 0; c < 2; ++c) acc[s][c] = (f32x4){0.f, 0.f, 0.f, 0.f};

    float nrm = 0.f, gac = 0.f;
    float qs[2][4], gpv[2][4];
    bf16x8 BH[2][2], BL[2][2];        // [buf][ct] proto frags

#define QLOADN(KC, SLOT)                                                      \
    {                                                                         \
        int c0 = (KC) * 32 + kq * 4;                                          \
        _Pragma("unroll")                                                     \
        for (int j = 0; j < 4; ++j) {                                         \
            qs[SLOT][j]  = qb[(size_t)(c0 + j) * HWW];                        \
            gpv[SLOT][j] = gp[c0 + j];                                        \
        }                                                                     \
    }

#define LOADB(KC, BUF)                                                        \
    {                                                                         \
        _Pragma("unroll")                                                     \
        for (int ct = 0; ct < 2; ++ct) {                                      \
            const unsigned short* p0 = Bb + (size_t)(KC) * 16384 +            \
                                       (w * 32 + ct * 16 + n) * 32 + g * 8;   \
            BH[BUF][ct] = *(const bf16x8*)(p0);                               \
            BL[BUF][ct] = *(const bf16x8*)(p0 + 8192);                        \
        }                                                                     \
    }

#define SPLITW(SLOT, BUF)                                                     \
    {                                                                         \
        unsigned int h[4], l[4];                                              \
        _Pragma("unroll")                                                     \
        for (int j = 0; j < 4; ++j) {                                         \
            float qv = qs[SLOT][j];                                           \
            unsigned int u = __float_as_uint(qv);                             \
            h[j] = u >> 16;                                                   \
            float lof = qv - __uint_as_float(u & 0xffff0000u);                \
            unsigned int ul = __float_as_uint(lof);                           \
            l[j] = (ul + 0x7fffu + ((ul >> 16) & 1u)) >> 16;                  \
            nrm = fmaf(qv, qv, nrm);                                          \
            gac = fmaf(qv, gpv[SLOT][j], gac);                                \
        }                                                                     \
        uint4 pk;                                                             \
        pk.x = h[0] | (h[1] << 16); pk.y = h[2] | (h[3] << 16);               \
        pk.z = l[0] | (l[1] << 16); pk.w = l[2] | (l[3] << 16);               \
        *(uint4*)&Qlds[BUF][spx * 72 + kq * 8] = pk;                          \
    }

    // ---- prologue: 2-deep q + B prefetch, split kc=0, publish ----
    QLOADN(0, 0);
    QLOADN(1, 1);
    LOADB(0, 0);
    LOADB(1, 1);
    SPLITW(0, 0);                 // waits q(0) via counted vmcnt (B younger)
    LBAR();

    // ---- main loop: 1 lgkm-only barrier per kc; prefetch survives it ----
#pragma unroll
    for (int kc = 0; kc < 8; ++kc) {
        if (kc + 2 < 8) QLOADN(kc + 2, kc & 1);
#pragma unroll
        for (int sub = 0; sub < 4; ++sub) {
            const unsigned short* rp = &Qlds[kc & 1][(sub * 16 + n) * 72 + g * 16];
            uint4 Aq = *(const uint4*)rp;
            uint4 Bq = *(const uint4*)(rp + 8);
            union { bf16x8 v; unsigned int u[4]; } QH, QL;
            QH.u[0] = Aq.x; QH.u[1] = Aq.y; QH.u[2] = Bq.x; QH.u[3] = Bq.y;
            QL.u[0] = Aq.z; QL.u[1] = Aq.w; QL.u[2] = Bq.z; QL.u[3] = Bq.w;
#pragma unroll
            for (int ct = 0; ct < 2; ++ct) {
                acc[sub][ct] = __builtin_amdgcn_mfma_f32_16x16x32_bf16(QH.v, BH[kc & 1][ct], acc[sub][ct], 0, 0, 0);
                acc[sub][ct] = __builtin_amdgcn_mfma_f32_16x16x32_bf16(QL.v, BH[kc & 1][ct], acc[sub][ct], 0, 0, 0);
                acc[sub][ct] = __builtin_amdgcn_mfma_f32_16x16x32_bf16(QH.v, BL[kc & 1][ct], acc[sub][ct], 0, 0, 0);
            }
        }
        if (kc + 2 < 8) LOADB(kc + 2, kc & 1);   // refill just-consumed B buf
        if (kc + 1 < 8) {
            SPLITW((kc + 1) & 1, (kc + 1) & 1);  // q(kc+1) -> other Q buf
            LBAR();
        }
    }

    // ---- |q|^2 and gproto-dot reduction (8 k-quad partials per px) ----
    nrm_l[w][spx] = nrm;
    gac_l[w][spx] = gac;
    __syncthreads();
    if (t < 64) {
        float n2 = 0.f, gs = 0.f;
#pragma unroll
        for (int i = 0; i < 8; ++i) { n2 += nrm_l[i][t]; gs += gac_l[i][t]; }
        float rn = 1.f / fmaxf(sqrtf(n2), NORM_EPS);
        rn_s[t] = rn;
        gd_s[t] = gs * rn;
    }
    __syncthreads();

    // ---- per-wave softmax partials (fixed shift 1.1; 32 protos/wave) ----
    // D-map: proto = 32w + 16ct + n (col), px = 16sub + 4g + r (row).
    float vf0 = validf[b * PPAD + w * 32 + n];
    float vf1 = validf[b * PPAD + w * 32 + 16 + n];
#pragma unroll
    for (int sub = 0; sub < 4; ++sub) {
#pragma unroll
        for (int r = 0; r < 4; ++r) {
            int px = sub * 16 + 4 * g + r;
            float rnv = rn_s[px];
            float d0 = acc[sub][0][r] * rnv;
            float d1 = acc[sub][1][r] * rnv;
            float l0 = (vf0 != 0.f) ? d0 : -1e30f;
            float l1 = (vf1 != 0.f) ? d1 : -1e30f;
            float e0 = __expf(l0 - 1.1f);
            float e1 = __expf(l1 - 1.1f);
            float s = e0 + e1;
            float nn = fmaf(e0, l0, e1 * l1);
#pragma unroll
            for (int m = 1; m < 16; m <<= 1) {
                s  += __shfl_xor(s, m);
                nn += __shfl_xor(nn, m);
            }
            if (n == 0) { S_l[w][px] = s; N_l[w][px] = nn; }
        }
    }
    __syncthreads();

    // ---- final merge: 8 wave-partials + global proto (once), store ----
    if (t < 64) {
        float gdv = gd_s[t];
        float eg = __expf(gdv - 1.1f);
        float S = eg, N = eg * gdv;
#pragma unroll
        for (int i = 0; i < 8; ++i) { S += S_l[i][t]; N += N_l[i][t]; }
        out[(size_t)b * HWW + px0 + t] = N / S;
    }

#undef QLOADN
#undef LOADB
#undef SPLITW
}

extern "C" void kernel_launch(void* const* d_in, const int* in_sizes, int n_in,
                              void* d_out, int out_size, void* d_ws, size_t ws_size,
                              hipStream_t stream) {
    const float* qry = (const float*)d_in[0];
    const float* sup = (const float*)d_in[1];
    const float* msk = (const float*)d_in[2];
    const float* bg  = (const float*)d_in[3];
    float* out = (float*)d_out;

    float* ws = (float*)d_ws;
    float* protos  = ws;                                   // [B][257][256] f32
    float* validf  = protos + (size_t)BB * PPAD * CC;      // [B][257]
    float* masksum = validf + (size_t)BB * PPAD;           // [B]
    unsigned short* Bimg = (unsigned short*)(masksum + BB); // [B][8][2][256][32] ushorts

    hipLaunchKernelGGL(k01, dim3(BB * CC + BB), dim3(256), 0, stream,
                       sup, msk, bg, protos, validf, masksum);
    hipLaunchKernelGGL(k2_norm, dim3(BB * PPAD), dim3(256), 0, stream, protos, masksum, Bimg);
    hipLaunchKernelGGL(k3_mfma, dim3(BB * (HWW / 64)), dim3(512), 0, stream,
                       qry, Bimg, protos, validf, out);
}